// Round 10
// baseline (262.457 us; speedup 1.0000x reference)
//
#include <hip/hip_runtime.h>
#include <stdint.h>
#include <math.h>

// ---------------------------------------------------------------------------
// Transformer block (B=2, S=2048, D=1024, H=16, hd=64, F=4096), post-LN.
// bf16 MFMA for all matmuls, fp32 accumulate. Threshold is 2% of |ref|max.
// GEMMs: 128x128 tile, BK=64, m97 2-barrier structure, 4 blocks/CU (R8 best).
// Attention: no-max softmax, K-split=2 (linear combine), 3 blocks/CU.
// ---------------------------------------------------------------------------

typedef __attribute__((ext_vector_type(4))) float f32x4;
typedef __attribute__((ext_vector_type(8))) short s16x8;

__device__ __forceinline__ float bf2f(short s){
  unsigned u = ((unsigned)(unsigned short)s) << 16;
  return __builtin_bit_cast(float, u);
}
__device__ __forceinline__ short f2bf(float f){
  unsigned u = __builtin_bit_cast(unsigned, f);
  unsigned r = (u + 0x7fffu + ((u >> 16) & 1u)) >> 16;   // RNE
  return (short)(unsigned short)r;
}

__device__ __forceinline__ void gload_lds16(const void* gp, void* lp){
  __builtin_amdgcn_global_load_lds(
      (__attribute__((address_space(1))) void*)const_cast<void*>(gp),
      (__attribute__((address_space(3))) void*)lp,
      16, 0, 0);
}

// ---------------- elementwise f32 -> bf16 ----------------------------------
__global__ void cvt_f32_bf16(const float* __restrict__ in, short* __restrict__ out, int n){
  int i = (blockIdx.x * blockDim.x + threadIdx.x) * 4;
  if (i < n){
    float4 v = *(const float4*)(in + i);
    short4 o;
    o.x = f2bf(v.x); o.y = f2bf(v.y); o.z = f2bf(v.z); o.w = f2bf(v.w);
    *(short4*)(out + i) = o;
  }
}

// ---------------- weight transpose+convert: in[R][C] f32 -> out[C][R] bf16 --
__global__ __launch_bounds__(256) void wtrans(const float* __restrict__ in,
                                              short* __restrict__ out, int R, int C){
  __shared__ float tile[32][33];
  int c0 = blockIdx.x * 32, r0 = blockIdx.y * 32;
  int tx = threadIdx.x, ty = threadIdx.y;        // block (32,8)
  #pragma unroll
  for (int j = 0; j < 4; ++j)
    tile[ty + j*8][tx] = in[(size_t)(r0 + ty + j*8) * C + c0 + tx];
  __syncthreads();
  #pragma unroll
  for (int j = 0; j < 4; ++j)
    out[(size_t)(c0 + ty + j*8) * R + r0 + tx] = f2bf(tile[tx][ty + j*8]);
}

// ---------------- V transpose: qkv[b*2048+s][2048+h*64+d] -> vt[(bh*64+d)][s]
__global__ __launch_bounds__(256) void vtrans(const short* __restrict__ qkv,
                                              short* __restrict__ vt){
  __shared__ short tile[32][33];
  int bh = blockIdx.z; int b = bh >> 4, h = bh & 15;
  int s0 = blockIdx.x * 32, d0 = blockIdx.y * 32;
  int tx = threadIdx.x, ty = threadIdx.y;
  #pragma unroll
  for (int j = 0; j < 4; ++j)
    tile[ty + j*8][tx] = qkv[(size_t)(b*2048 + s0 + ty + j*8) * 3072 + 2048 + h*64 + d0 + tx];
  __syncthreads();
  #pragma unroll
  for (int j = 0; j < 4; ++j)
    vt[(size_t)(bh*64 + d0 + ty + j*8) * 2048 + s0 + tx] = tile[tx][ty + j*8];
}

// ---------------- GEMM: C[M][N] = A[M][K](bf16) @ BT[N][K](bf16)^T ---------
// 128x128 tile, BK=64, 4 waves (2x2), m97 2-barrier loop, 4 blocks/CU.
// EPI: 0 = bf16 (acc+bias)                         (qkv)
//      2 = gelu(acc+bias) bf16                     (fc)
//      4 = raw bf16 partial to o[blockIdx.z]       (split-K; bias in LN fuse)
#define GBM 128
#define GBN 128
#define GBK 64

__global__ __launch_bounds__(256, 4) void gemm_bf16(
    const short* __restrict__ A, const short* __restrict__ BT,
    const float* __restrict__ bias,
    void* __restrict__ out, void* __restrict__ out2,
    void* __restrict__ out3, void* __restrict__ out4,
    int M, int N, int K, int EPI, int KS)
{
  __shared__ short sA[GBM * GBK];   // 16 KB, rows of 64 shorts (128 B), XOR-swizzled slots
  __shared__ short sB[GBN * GBK];   // 16 KB
  const int t = threadIdx.x;
  const int lane = t & 63;
  const int w = t >> 6;
  const int wr = w >> 1, wc = w & 1;            // 2x2 wave grid, each wave 64x64
  const int lrow = lane & 15;
  const int lk = lane >> 4;

  // bijective XCD-chunked remap: XCD x computes a contiguous wg range
  const int gx = gridDim.x;
  const int nwg = gx * gridDim.y;               // all grids here: nwg % 8 == 0
  const int P = blockIdx.y * gx + blockIdx.x;
  const int wg = (P & 7) * (nwg >> 3) + (P >> 3);
  const int m0 = (wg / gx) * GBM, n0 = (wg % gx) * GBN;

  const int Kspl = K / KS;
  const int kbeg = blockIdx.z * Kspl;

  f32x4 acc[4][4] = {};

  for (int kk = kbeg; kk < kbeg + Kspl; kk += GBK){
    __syncthreads();                            // prior reads done before overwrite
    #pragma unroll
    for (int r = 0; r < 4; ++r){                // stage A: 4 rounds x 4 KB
      int o = r * 4096 + t * 16;                // linear LDS byte offset
      int row = o >> 7;                         // 128 B per row
      int phys = (o >> 4) & 7;                  // 16B slot within row
      int lsl = phys ^ (row & 7);               // inverse-swizzled source chunk
      gload_lds16(A + (size_t)(m0 + row) * K + kk + lsl * 8, (char*)sA + o);
    }
    #pragma unroll
    for (int r = 0; r < 4; ++r){                // stage BT
      int o = r * 4096 + t * 16;
      int row = o >> 7;
      int phys = (o >> 4) & 7;
      int lsl = phys ^ (row & 7);
      gload_lds16(BT + (size_t)(n0 + row) * K + kk + lsl * 8, (char*)sB + o);
    }
    __syncthreads();                            // drains vmcnt before barrier

    #pragma unroll
    for (int kc = 0; kc < 2; ++kc){
      s16x8 af[4], bf[4];
      #pragma unroll
      for (int rt = 0; rt < 4; ++rt){
        int row = wr*64 + rt*16 + lrow;
        int slot = (kc*4 + lk) ^ (row & 7);     // swizzled read
        af[rt] = *(const s16x8*)&sA[row*64 + slot*8];
      }
      #pragma unroll
      for (int ct = 0; ct < 4; ++ct){
        int row = wc*64 + ct*16 + lrow;
        int slot = (kc*4 + lk) ^ (row & 7);
        bf[ct] = *(const s16x8*)&sB[row*64 + slot*8];
      }
      #pragma unroll
      for (int rt = 0; rt < 4; ++rt)
        #pragma unroll
        for (int ct = 0; ct < 4; ++ct)
          acc[rt][ct] = __builtin_amdgcn_mfma_f32_16x16x32_bf16(af[rt], bf[ct], acc[rt][ct], 0, 0, 0);
    }
  }

  void* pz = (blockIdx.z == 0) ? out : (blockIdx.z == 1) ? out2
           : (blockIdx.z == 2) ? out3 : out4;
  #pragma unroll
  for (int rt = 0; rt < 4; ++rt){
    #pragma unroll
    for (int ct = 0; ct < 4; ++ct){
      #pragma unroll
      for (int r = 0; r < 4; ++r){
        int row = m0 + wr*64 + rt*16 + lk*4 + r;    // C/D: row=(lane>>4)*4+reg
        int col = n0 + wc*64 + ct*16 + lrow;        //      col=lane&15
        size_t idx = (size_t)row * N + col;
        if (EPI == 4){
          ((short*)pz)[idx] = f2bf(acc[rt][ct][r]);
        } else {
          float v = acc[rt][ct][r] + bias[col];
          if (EPI == 0){
            ((short*)out)[idx] = f2bf(v);
          } else {
            float g = 0.5f * v * (1.0f + erff(v * 0.70710678118654752f));
            ((short*)out)[idx] = f2bf(g);
          }
        }
      }
    }
  }
}

// ---------------- flash attention (causal), no-max softmax, K-split=2 -------
// Scores bounded (|s|~3 << 88): p = exp(s) directly; masked -> exp -> 0.
// Row-sums via ones-MFMA. Linear combine across k-splits (no max state):
// this kernel stores RAW partial O (bf16) + partial sums; combine divides.
// Grid 1024: all 32 blocks of one (b,h) share an XCD.
__global__ __launch_bounds__(256, 3) void attn_kernel(
    const short* __restrict__ qkv, const short* __restrict__ vt,
    short* __restrict__ oa0, short* __restrict__ oa1,
    float* __restrict__ sums0, float* __restrict__ sums1)
{
  const int P = blockIdx.x;
  const int xcd = P & 7;
  const int idx = P >> 3;               // 0..127
  const int ks = idx & 1;
  const int pairi = (idx >> 1) & 15;    // 0..15
  const int bh = xcd + ((idx >> 5) << 3);
  const int b = bh >> 4, h = bh & 15;
  const int t  = threadIdx.x;
  const int lane = t & 63;
  const int w = t >> 6;
  const int lrow = lane & 15, lk = lane >> 4;

  short* oa = ks ? oa1 : oa0;
  float* sums = ks ? sums1 : sums0;

  __shared__ short sK[2][64*64];        // 2 x 8 KB, rows of 64 shorts, XOR-swizzled
  __shared__ short sV[2][64*64];        // 2 x 8 KB
  __shared__ short sP[4][16][68];       // per-wave P tile, +4 shorts pad

  const size_t kgbase = (size_t)(b*2048)*3072 + 1024 + h*64;   // K rows in qkv
  const size_t vgbase = (size_t)((b*16 + h)*64)*2048;          // V^T rows in vt

  s16x8 bones;                          // all-ones bf16 B fragment
  #pragma unroll
  for (int i = 0; i < 8; ++i) bones[i] = (short)0x3F80;

  auto stage = [&](int buf, int k0){
    #pragma unroll
    for (int r2 = 0; r2 < 2; ++r2){     // 8 KB per tile: 2 rounds x 4 KB
      int o = r2*4096 + t*16;           // linear LDS byte offset
      int row = o >> 7;                 // 128 B per row
      int lsl = ((o >> 4) & 7) ^ (row & 7);   // inverse-swizzled source chunk
      gload_lds16(qkv + kgbase + (size_t)(k0 + row)*3072 + lsl*8, (char*)sK[buf] + o);
      gload_lds16(vt  + vgbase + (size_t)row*2048 + k0   + lsl*8, (char*)sV[buf] + o);
    }
  };

  for (int pass = 0; pass < 2; ++pass){
    const int qt = pass ? 31 - pairi : pairi;
    const int q0 = qt * 64;
    const int qbase = q0 + w * 16;

    const int nt = qt + 1;
    const int half = (nt + 1) >> 1;
    const int kstart = ks ? half : 0;
    const int kend   = ks ? nt : half;

    s16x8 aq[2];
    #pragma unroll
    for (int kc = 0; kc < 2; ++kc)
      aq[kc] = *(const s16x8*)(qkv + (size_t)(b*2048 + qbase + lrow)*3072 + h*64 + kc*32 + lk*8);

    f32x4 oacc[4] = {};
    f32x4 sumacc = {};                  // row-sums of P, via ones-MFMA

    __syncthreads();                    // prior pass's reads complete
    if (kend > kstart) stage(0, kstart * 64);
    __syncthreads();
    int cur = 0;

    for (int ktile = kstart; ktile < kend; ++ktile){
      const int k0 = ktile * 64;
      if (ktile + 1 < kend) stage(cur ^ 1, k0 + 64);   // prefetch next tile

      f32x4 sacc[4] = {};
      __builtin_amdgcn_s_setprio(1);
      #pragma unroll
      for (int kc = 0; kc < 2; ++kc){
        #pragma unroll
        for (int ct = 0; ct < 4; ++ct){
          int row = ct*16 + lrow;
          int slot = (kc*4 + lk) ^ (row & 7);
          s16x8 bk = *(const s16x8*)&sK[cur][row*64 + slot*8];
          sacc[ct] = __builtin_amdgcn_mfma_f32_16x16x32_bf16(aq[kc], bk, sacc[ct], 0, 0, 0);
        }
      }
      __builtin_amdgcn_s_setprio(0);

      // p = exp(s/8 | mask) straight to bf16 P tile (no max, no reduction)
      const bool need_mask = (k0 + 63 > qbase);
      #pragma unroll
      for (int ct = 0; ct < 4; ++ct){
        #pragma unroll
        for (int r = 0; r < 4; ++r){
          float v = sacc[ct][r] * 0.125f;               // 1/sqrt(64)
          if (need_mask){
            int qi = qbase + lk*4 + r;
            int ki = k0 + ct*16 + lrow;
            if (ki > qi) v = -10000.0f;                 // exp -> exactly 0
          }
          sP[w][lk*4 + r][ct*16 + lrow] = f2bf(__expf(v));
        }
      }

      s16x8 pa[2];
      #pragma unroll
      for (int kc = 0; kc < 2; ++kc)
        pa[kc] = *(const s16x8*)&sP[w][lrow][kc*32 + lk*8];
      __builtin_amdgcn_s_setprio(1);
      #pragma unroll
      for (int dt = 0; dt < 4; ++dt){
        #pragma unroll
        for (int kc = 0; kc < 2; ++kc){
          int row = dt*16 + lrow;
          int slot = (kc*4 + lk) ^ (row & 7);
          s16x8 bv = *(const s16x8*)&sV[cur][row*64 + slot*8];
          oacc[dt] = __builtin_amdgcn_mfma_f32_16x16x32_bf16(pa[kc], bv, oacc[dt], 0, 0, 0);
        }
      }
      #pragma unroll
      for (int kc = 0; kc < 2; ++kc)
        sumacc = __builtin_amdgcn_mfma_f32_16x16x32_bf16(pa[kc], bones, sumacc, 0, 0, 0);
      __builtin_amdgcn_s_setprio(0);

      __syncthreads();
      cur ^= 1;
    }

    // store RAW partials (combine kernel divides)
    #pragma unroll
    for (int r = 0; r < 4; ++r){
      int row = b*2048 + qbase + lk*4 + r;
      #pragma unroll
      for (int dt = 0; dt < 4; ++dt){
        int col = h*64 + dt*16 + lrow;
        oa[(size_t)row * 1024 + col] = f2bf(oacc[dt][r]);
      }
      if (lrow == 0) sums[row*16 + h] = sumacc[r];
    }
  }
}

// ---------------- combine k-split partials: ob = (o0+o1)/(s0+s1) ------------
__global__ __launch_bounds__(256) void attn_combine(
    const short* __restrict__ oa0, const short* __restrict__ oa1,
    const float* __restrict__ sums0, const float* __restrict__ sums1,
    short* __restrict__ ob)
{
  const int row = blockIdx.x;
  const int t = threadIdx.x;
  const int col = t * 4;
  const int h = col >> 6;
  const float inv = 1.0f / (sums0[row*16 + h] + sums1[row*16 + h]);
  const size_t base = (size_t)row*1024 + col;
  short4 a = *(const short4*)(oa0 + base);
  short4 c = *(const short4*)(oa1 + base);
  short4 o;
  o.x = f2bf((bf2f(a.x) + bf2f(c.x)) * inv);
  o.y = f2bf((bf2f(a.y) + bf2f(c.y)) * inv);
  o.z = f2bf((bf2f(a.z) + bf2f(c.z)) * inv);
  o.w = f2bf((bf2f(a.w) + bf2f(c.w)) * inv);
  *(short4*)(ob + base) = o;
}

// -------- LN fused with split-K4 reduce + residual --------------------------
// v = p0+p1+p2+p3 (bf16 partials) + bias + (resid_bf | resid_f); out = LN(v)
__global__ __launch_bounds__(256) void ln_fused(
    const short* __restrict__ p0, const short* __restrict__ p1,
    const short* __restrict__ p2, const short* __restrict__ p3,
    const float* __restrict__ bias,
    const short* __restrict__ resid_bf, const float* __restrict__ resid_f,
    const float* __restrict__ g, const float* __restrict__ b,
    void* __restrict__ out, int bf16_out)
{
  const int row = blockIdx.x;
  const int t = threadIdx.x;
  const size_t base = (size_t)row*1024 + t*4;
  short4 a0 = *(const short4*)(p0 + base);
  short4 a1 = *(const short4*)(p1 + base);
  short4 a2 = *(const short4*)(p2 + base);
  short4 a3 = *(const short4*)(p3 + base);
  float4 bi = *(const float4*)(bias + t*4);
  float r0, r1, r2, r3;
  if (resid_bf){
    short4 rr = *(const short4*)(resid_bf + base);
    r0 = bf2f(rr.x); r1 = bf2f(rr.y); r2 = bf2f(rr.z); r3 = bf2f(rr.w);
  } else {
    float4 rr = *(const float4*)(resid_f + base);
    r0 = rr.x; r1 = rr.y; r2 = rr.z; r3 = rr.w;
  }
  float v0 = bf2f(a0.x) + bf2f(a1.x) + bf2f(a2.x) + bf2f(a3.x) + bi.x + r0;
  float v1 = bf2f(a0.y) + bf2f(a1.y) + bf2f(a2.y) + bf2f(a3.y) + bi.y + r1;
  float v2 = bf2f(a0.z) + bf2f(a1.z) + bf2f(a2.z) + bf2f(a3.z) + bi.z + r2;
  float v3 = bf2f(a0.w) + bf2f(a1.w) + bf2f(a2.w) + bf2f(a3.w) + bi.w + r3;
  float s = v0 + v1 + v2 + v3;
  float q = v0*v0 + v1*v1 + v2*v2 + v3*v3;
  #pragma unroll
  for (int off = 1; off < 64; off <<= 1){
    s += __shfl_xor(s, off, 64);
    q += __shfl_xor(q, off, 64);
  }
  __shared__ float ss[4], sq[4];
  if ((t & 63) == 0){ ss[t >> 6] = s; sq[t >> 6] = q; }
  __syncthreads();
  s = ss[0] + ss[1] + ss[2] + ss[3];
  q = sq[0] + sq[1] + sq[2] + sq[3];
  float mu = s * (1.0f/1024.0f);
  float var = q * (1.0f/1024.0f) - mu*mu;
  float rs = rsqrtf(var + 1e-5f);
  float4 gg = *(const float4*)(g + t*4);
  float4 bb = *(const float4*)(b + t*4);
  float o0 = (v0 - mu)*rs*gg.x + bb.x;
  float o1 = (v1 - mu)*rs*gg.y + bb.y;
  float o2 = (v2 - mu)*rs*gg.z + bb.z;
  float o3 = (v3 - mu)*rs*gg.w + bb.w;
  if (bf16_out){
    short4 o; o.x = f2bf(o0); o.y = f2bf(o1); o.z = f2bf(o2); o.w = f2bf(o3);
    *(short4*)((short*)out + base) = o;
  } else {
    float4 o = {o0, o1, o2, o3};
    *(float4*)((float*)out + base) = o;
  }
}

// ---------------------------------------------------------------------------
extern "C" void kernel_launch(void* const* d_in, const int* in_sizes, int n_in,
                              void* d_out, int out_size, void* d_ws, size_t ws_size,
                              hipStream_t stream) {
  const float* x      = (const float*)d_in[0];
  const float* w_attn = (const float*)d_in[1];
  const float* b_attn = (const float*)d_in[2];
  const float* w_o    = (const float*)d_in[3];
  const float* b_o    = (const float*)d_in[4];
  const float* ln1_g  = (const float*)d_in[5];
  const float* ln1_b  = (const float*)d_in[6];
  const float* w_fc   = (const float*)d_in[7];
  const float* b_fc   = (const float*)d_in[8];
  const float* w_pr   = (const float*)d_in[9];
  const float* b_pr   = (const float*)d_in[10];
  const float* ln2_g  = (const float*)d_in[11];
  const float* ln2_b  = (const float*)d_in[12];

  char* ws = (char*)d_ws;
  const size_t MB = 1048576;
  // lifetimes: high-water 96 MiB
  short* waT  = (short*)(ws + 0);          // 6 MiB  (steps 2-6; dead after qkv)
  float* sums0= (float*)(ws + 0);          // 256 KiB (steps 8a-8b, aliases waT)
  float* sums1= (float*)(ws + 1*MB);       // 256 KiB
  short* wfT  = (short*)(ws + 6*MB);       // 8 MiB  (steps 2-11)
  short* wpT  = (short*)(ws + 14*MB);      // 8 MiB  (steps 2-12)
  short* woT  = (short*)(ws + 22*MB);      // 2 MiB  (steps 2-9)
  short* xb   = (short*)(ws + 24*MB);      // 8 MiB  (steps 1-6)
  short* vt   = (short*)(ws + 24*MB);      // 8 MiB  (steps 7-8)
  short* pp2  = (short*)(ws + 24*MB);      // 8 MiB  (steps 9-10, 12-13)
  short* qkvb = (short*)(ws + 32*MB);      // 24 MiB (steps 6-8)
  short* fb   = (short*)(ws + 32*MB);      // 32 MiB (steps 11-12)
  short* ob   = (short*)(ws + 56*MB);      // 8 MiB  (steps 8b-9)
  short* oa0  = (short*)(ws + 64*MB);      // 8 MiB  (steps 8a-8b)
  short* pp0  = (short*)(ws + 64*MB);      // 8 MiB  (steps 9-10, 12-13)
  short* oa1  = (short*)(ws + 72*MB);      // 8 MiB  (steps 8a-8b)
  short* pp1  = (short*)(ws + 72*MB);      // 8 MiB
  short* nb   = (short*)(ws + 80*MB);      // 8 MiB  (steps 10-13)
  short* pp3  = (short*)(ws + 88*MB);      // 8 MiB  (steps 9-10, 12-13)

  const int M = 4096;

  // 1. x -> bf16
  cvt_f32_bf16<<<dim3(M*1024/1024), dim3(256), 0, stream>>>(x, xb, M*1024);
  // 2-5. weight transposes (f32 [K][N] -> bf16 [N][K])
  wtrans<<<dim3(3072/32, 1024/32), dim3(32,8), 0, stream>>>(w_attn, waT, 1024, 3072);
  wtrans<<<dim3(1024/32, 1024/32), dim3(32,8), 0, stream>>>(w_o,   woT, 1024, 1024);
  wtrans<<<dim3(4096/32, 1024/32), dim3(32,8), 0, stream>>>(w_fc,  wfT, 1024, 4096);
  wtrans<<<dim3(1024/32, 4096/32), dim3(32,8), 0, stream>>>(w_pr,  wpT, 4096, 1024);
  // 6. qkv = x @ w_attn + b_attn  (bf16 out); 24x32 = 768 blocks (3/CU)
  gemm_bf16<<<dim3(3072/GBN, M/GBM), dim3(256), 0, stream>>>(
      xb, waT, b_attn, qkvb, nullptr, nullptr, nullptr, M, 3072, 1024, 0, 1);
  // 7. vt = transpose of V per (b,h)
  vtrans<<<dim3(2048/32, 64/32, 32), dim3(32,8), 0, stream>>>(qkvb, vt);
  // 8a. attention partials (K-split=2): 1024 blocks, 3/CU LDS-capped
  attn_kernel<<<dim3(1024), dim3(256), 0, stream>>>(qkvb, vt, oa0, oa1, sums0, sums1);
  // 8b. combine -> ob (bf16)
  attn_combine<<<dim3(M), dim3(256), 0, stream>>>(oa0, oa1, sums0, sums1, ob);
  // 9. o-proj split-K4: pp0..3 = ob @ w_o partials (bf16); 8x32x4 = 1024 blocks
  gemm_bf16<<<dim3(1024/GBN, M/GBM, 4), dim3(256), 0, stream>>>(
      ob, woT, nullptr, pp0, pp1, pp2, pp3, M, 1024, 1024, 4, 4);
  // 10. n = LN(pp* + b_o + x) -> nb (bf16)
  ln_fused<<<dim3(M), dim3(256), 0, stream>>>(pp0, pp1, pp2, pp3, b_o,
                                              nullptr, x, ln1_g, ln1_b, nb, 1);
  // 11. f = gelu(n @ w_fc + b_fc) -> fb (bf16); 32x32 = 1024 blocks (4/CU)
  gemm_bf16<<<dim3(4096/GBN, M/GBM), dim3(256), 0, stream>>>(
      nb, wfT, b_fc, fb, nullptr, nullptr, nullptr, M, 4096, 1024, 2, 1);
  // 12. r2 split-K4: pp0..3 = fb @ w_pr partials (bf16); 8x32x4 = 1024 blocks
  gemm_bf16<<<dim3(1024/GBN, M/GBM, 4), dim3(256), 0, stream>>>(
      fb, wpT, nullptr, pp0, pp1, pp2, pp3, M, 1024, 4096, 4, 4);
  // 13. h = LN(pp* + b_pr + nb) -> d_out (f32)
  ln_fused<<<dim3(M), dim3(256), 0, stream>>>(pp0, pp1, pp2, pp3, b_pr,
                                              nb, nullptr, ln2_g, ln2_b, d_out, 0);
}

// Round 11
// 254.703 us; speedup vs baseline: 1.0304x; 1.0304x over previous
//
#include <hip/hip_runtime.h>
#include <stdint.h>
#include <math.h>

// ---------------------------------------------------------------------------
// Transformer block (B=2, S=2048, D=1024, H=16, hd=64, F=4096), post-LN.
// bf16 MFMA for all matmuls, fp32 accumulate. Threshold is 2% of |ref|max.
// GEMMs: 128x128 tile, BK=64, m97 2-barrier structure, 4 blocks/CU (R8 best).
// Attention: no-max softmax, MERGED paired q-tiles (stage shared k-prefix once).
// ---------------------------------------------------------------------------

typedef __attribute__((ext_vector_type(4))) float f32x4;
typedef __attribute__((ext_vector_type(8))) short s16x8;

__device__ __forceinline__ float bf2f(short s){
  unsigned u = ((unsigned)(unsigned short)s) << 16;
  return __builtin_bit_cast(float, u);
}
__device__ __forceinline__ short f2bf(float f){
  unsigned u = __builtin_bit_cast(unsigned, f);
  unsigned r = (u + 0x7fffu + ((u >> 16) & 1u)) >> 16;   // RNE
  return (short)(unsigned short)r;
}

__device__ __forceinline__ void gload_lds16(const void* gp, void* lp){
  __builtin_amdgcn_global_load_lds(
      (__attribute__((address_space(1))) void*)const_cast<void*>(gp),
      (__attribute__((address_space(3))) void*)lp,
      16, 0, 0);
}

// ---------------- elementwise f32 -> bf16 ----------------------------------
__global__ void cvt_f32_bf16(const float* __restrict__ in, short* __restrict__ out, int n){
  int i = (blockIdx.x * blockDim.x + threadIdx.x) * 4;
  if (i < n){
    float4 v = *(const float4*)(in + i);
    short4 o;
    o.x = f2bf(v.x); o.y = f2bf(v.y); o.z = f2bf(v.z); o.w = f2bf(v.w);
    *(short4*)(out + i) = o;
  }
}

// ---------------- weight transpose+convert: in[R][C] f32 -> out[C][R] bf16 --
__global__ __launch_bounds__(256) void wtrans(const float* __restrict__ in,
                                              short* __restrict__ out, int R, int C){
  __shared__ float tile[32][33];
  int c0 = blockIdx.x * 32, r0 = blockIdx.y * 32;
  int tx = threadIdx.x, ty = threadIdx.y;        // block (32,8)
  #pragma unroll
  for (int j = 0; j < 4; ++j)
    tile[ty + j*8][tx] = in[(size_t)(r0 + ty + j*8) * C + c0 + tx];
  __syncthreads();
  #pragma unroll
  for (int j = 0; j < 4; ++j)
    out[(size_t)(c0 + ty + j*8) * R + r0 + tx] = f2bf(tile[tx][ty + j*8]);
}

// ---------------- V transpose: qkv[b*2048+s][2048+h*64+d] -> vt[(bh*64+d)][s]
__global__ __launch_bounds__(256) void vtrans(const short* __restrict__ qkv,
                                              short* __restrict__ vt){
  __shared__ short tile[32][33];
  int bh = blockIdx.z; int b = bh >> 4, h = bh & 15;
  int s0 = blockIdx.x * 32, d0 = blockIdx.y * 32;
  int tx = threadIdx.x, ty = threadIdx.y;
  #pragma unroll
  for (int j = 0; j < 4; ++j)
    tile[ty + j*8][tx] = qkv[(size_t)(b*2048 + s0 + ty + j*8) * 3072 + 2048 + h*64 + d0 + tx];
  __syncthreads();
  #pragma unroll
  for (int j = 0; j < 4; ++j)
    vt[(size_t)(bh*64 + d0 + ty + j*8) * 2048 + s0 + tx] = tile[tx][ty + j*8];
}

// ---------------- GEMM: C[M][N] = A[M][K](bf16) @ BT[N][K](bf16)^T ---------
// 128x128 tile, BK=64, 4 waves (2x2), m97 2-barrier loop, 4 blocks/CU.
// EPI: 0 = bf16 (acc+bias)                         (qkv)
//      2 = gelu(acc+bias) bf16                     (fc)
//      4 = raw bf16 partial to o[blockIdx.z]       (split-K; bias in LN fuse)
#define GBM 128
#define GBN 128
#define GBK 64

__global__ __launch_bounds__(256, 4) void gemm_bf16(
    const short* __restrict__ A, const short* __restrict__ BT,
    const float* __restrict__ bias,
    void* __restrict__ out, void* __restrict__ out2,
    void* __restrict__ out3, void* __restrict__ out4,
    int M, int N, int K, int EPI, int KS)
{
  __shared__ short sA[GBM * GBK];   // 16 KB, rows of 64 shorts (128 B), XOR-swizzled slots
  __shared__ short sB[GBN * GBK];   // 16 KB
  const int t = threadIdx.x;
  const int lane = t & 63;
  const int w = t >> 6;
  const int wr = w >> 1, wc = w & 1;            // 2x2 wave grid, each wave 64x64
  const int lrow = lane & 15;
  const int lk = lane >> 4;

  // bijective XCD-chunked remap: XCD x computes a contiguous wg range
  const int gx = gridDim.x;
  const int nwg = gx * gridDim.y;               // all grids here: nwg % 8 == 0
  const int P = blockIdx.y * gx + blockIdx.x;
  const int wg = (P & 7) * (nwg >> 3) + (P >> 3);
  const int m0 = (wg / gx) * GBM, n0 = (wg % gx) * GBN;

  const int Kspl = K / KS;
  const int kbeg = blockIdx.z * Kspl;

  f32x4 acc[4][4] = {};

  for (int kk = kbeg; kk < kbeg + Kspl; kk += GBK){
    __syncthreads();                            // prior reads done before overwrite
    #pragma unroll
    for (int r = 0; r < 4; ++r){                // stage A: 4 rounds x 4 KB
      int o = r * 4096 + t * 16;                // linear LDS byte offset
      int row = o >> 7;                         // 128 B per row
      int phys = (o >> 4) & 7;                  // 16B slot within row
      int lsl = phys ^ (row & 7);               // inverse-swizzled source chunk
      gload_lds16(A + (size_t)(m0 + row) * K + kk + lsl * 8, (char*)sA + o);
    }
    #pragma unroll
    for (int r = 0; r < 4; ++r){                // stage BT
      int o = r * 4096 + t * 16;
      int row = o >> 7;
      int phys = (o >> 4) & 7;
      int lsl = phys ^ (row & 7);
      gload_lds16(BT + (size_t)(n0 + row) * K + kk + lsl * 8, (char*)sB + o);
    }
    __syncthreads();                            // drains vmcnt before barrier

    #pragma unroll
    for (int kc = 0; kc < 2; ++kc){
      s16x8 af[4], bf[4];
      #pragma unroll
      for (int rt = 0; rt < 4; ++rt){
        int row = wr*64 + rt*16 + lrow;
        int slot = (kc*4 + lk) ^ (row & 7);     // swizzled read
        af[rt] = *(const s16x8*)&sA[row*64 + slot*8];
      }
      #pragma unroll
      for (int ct = 0; ct < 4; ++ct){
        int row = wc*64 + ct*16 + lrow;
        int slot = (kc*4 + lk) ^ (row & 7);
        bf[ct] = *(const s16x8*)&sB[row*64 + slot*8];
      }
      #pragma unroll
      for (int rt = 0; rt < 4; ++rt)
        #pragma unroll
        for (int ct = 0; ct < 4; ++ct)
          acc[rt][ct] = __builtin_amdgcn_mfma_f32_16x16x32_bf16(af[rt], bf[ct], acc[rt][ct], 0, 0, 0);
    }
  }

  void* pz = (blockIdx.z == 0) ? out : (blockIdx.z == 1) ? out2
           : (blockIdx.z == 2) ? out3 : out4;
  #pragma unroll
  for (int rt = 0; rt < 4; ++rt){
    #pragma unroll
    for (int ct = 0; ct < 4; ++ct){
      #pragma unroll
      for (int r = 0; r < 4; ++r){
        int row = m0 + wr*64 + rt*16 + lk*4 + r;    // C/D: row=(lane>>4)*4+reg
        int col = n0 + wc*64 + ct*16 + lrow;        //      col=lane&15
        size_t idx = (size_t)row * N + col;
        if (EPI == 4){
          ((short*)pz)[idx] = f2bf(acc[rt][ct][r]);
        } else {
          float v = acc[rt][ct][r] + bias[col];
          if (EPI == 0){
            ((short*)out)[idx] = f2bf(v);
          } else {
            float g = 0.5f * v * (1.0f + erff(v * 0.70710678118654752f));
            ((short*)out)[idx] = f2bf(g);
          }
        }
      }
    }
  }
}

// ---------------- attention (causal), no-max softmax, MERGED pairs ----------
// Each block handles q-tiles A=pairi and B=31-pairi in ONE k-loop over tiles
// 0..31-pairi: B accumulates every tile, A only while ktile <= pairi. The
// shared k-prefix is staged ONCE (32-pairi stages vs 33 before).
// Pair decode puts complementary-cost blocks (p, 15-p) on the same CU slot
// under round-robin dispatch (blocks idx and idx+32): cost sum = 47 = const.
// 512 blocks; all blocks of one (b,h) share an XCD (P%8).
__global__ __launch_bounds__(256, 2) void attn_kernel(
    const short* __restrict__ qkv, const short* __restrict__ vt,
    short* __restrict__ ob)
{
  const int P = blockIdx.x;
  const int xcd = P & 7;
  const int idx = P >> 3;               // 0..63
  const int raw = idx & 15;
  const int grp = idx >> 4;             // 0..3
  const int pairi = (grp & 2) ? (15 - raw) : raw;   // CU-pair balancing
  const int bh = xcd + (grp << 3);
  const int b = bh >> 4, h = bh & 15;
  const int t  = threadIdx.x;
  const int lane = t & 63;
  const int w = t >> 6;
  const int lrow = lane & 15, lk = lane >> 4;

  __shared__ short sK[2][64*64];        // 2 x 8 KB, rows of 64 shorts, XOR-swizzled
  __shared__ short sV[2][64*64];        // 2 x 8 KB
  __shared__ short sP[4][16][68];       // per-wave P tile, +4 shorts pad

  const size_t kgbase = (size_t)(b*2048)*3072 + 1024 + h*64;   // K rows in qkv
  const size_t vgbase = (size_t)((b*16 + h)*64)*2048;          // V^T rows in vt

  s16x8 bones;                          // all-ones bf16 B fragment
  #pragma unroll
  for (int i = 0; i < 8; ++i) bones[i] = (short)0x3F80;

  auto stage = [&](int buf, int k0){
    #pragma unroll
    for (int r2 = 0; r2 < 2; ++r2){     // 8 KB per tile: 2 rounds x 4 KB
      int o = r2*4096 + t*16;           // linear LDS byte offset
      int row = o >> 7;                 // 128 B per row
      int lsl = ((o >> 4) & 7) ^ (row & 7);   // inverse-swizzled source chunk
      gload_lds16(qkv + kgbase + (size_t)(k0 + row)*3072 + lsl*8, (char*)sK[buf] + o);
      gload_lds16(vt  + vgbase + (size_t)row*2048 + k0   + lsl*8, (char*)sV[buf] + o);
    }
  };

  const int qtA = pairi;                // tiles 0..qtA
  const int qtB = 31 - pairi;           // tiles 0..qtB (qtB >= 16 > qtA)
  const int qbaseA = qtA*64 + w*16;
  const int qbaseB = qtB*64 + w*16;

  s16x8 aqA[2], aqB[2];
  #pragma unroll
  for (int kc = 0; kc < 2; ++kc){
    aqA[kc] = *(const s16x8*)(qkv + (size_t)(b*2048 + qbaseA + lrow)*3072 + h*64 + kc*32 + lk*8);
    aqB[kc] = *(const s16x8*)(qkv + (size_t)(b*2048 + qbaseB + lrow)*3072 + h*64 + kc*32 + lk*8);
  }

  f32x4 oaccA[4] = {}, oaccB[4] = {};
  f32x4 sumA = {}, sumB = {};

  const int ntA = qtA + 1;
  const int ntB = qtB + 1;              // loop bound
  stage(0, 0);
  __syncthreads();
  int cur = 0;

  for (int ktile = 0; ktile < ntB; ++ktile){
    const int k0 = ktile * 64;
    if (ktile + 1 < ntB) stage(cur ^ 1, k0 + 64);   // prefetch next tile

    // ================= set B (every tile) =================
    {
      f32x4 sacc[4] = {};
      __builtin_amdgcn_s_setprio(1);
      #pragma unroll
      for (int kc = 0; kc < 2; ++kc){
        #pragma unroll
        for (int ct = 0; ct < 4; ++ct){
          int row = ct*16 + lrow;
          int slot = (kc*4 + lk) ^ (row & 7);
          s16x8 bk = *(const s16x8*)&sK[cur][row*64 + slot*8];
          sacc[ct] = __builtin_amdgcn_mfma_f32_16x16x32_bf16(aqB[kc], bk, sacc[ct], 0, 0, 0);
        }
      }
      __builtin_amdgcn_s_setprio(0);

      const bool need_mask = (k0 + 63 > qbaseB);
      #pragma unroll
      for (int ct = 0; ct < 4; ++ct){
        #pragma unroll
        for (int r = 0; r < 4; ++r){
          float v = sacc[ct][r] * 0.125f;               // 1/sqrt(64)
          if (need_mask){
            int qi = qbaseB + lk*4 + r;
            int ki = k0 + ct*16 + lrow;
            if (ki > qi) v = -10000.0f;                 // exp -> exactly 0
          }
          sP[w][lk*4 + r][ct*16 + lrow] = f2bf(__expf(v));
        }
      }

      s16x8 pa[2];
      #pragma unroll
      for (int kc = 0; kc < 2; ++kc)
        pa[kc] = *(const s16x8*)&sP[w][lrow][kc*32 + lk*8];
      __builtin_amdgcn_s_setprio(1);
      #pragma unroll
      for (int dt = 0; dt < 4; ++dt){
        #pragma unroll
        for (int kc = 0; kc < 2; ++kc){
          int row = dt*16 + lrow;
          int slot = (kc*4 + lk) ^ (row & 7);
          s16x8 bv = *(const s16x8*)&sV[cur][row*64 + slot*8];
          oaccB[dt] = __builtin_amdgcn_mfma_f32_16x16x32_bf16(pa[kc], bv, oaccB[dt], 0, 0, 0);
        }
      }
      #pragma unroll
      for (int kc = 0; kc < 2; ++kc)
        sumB = __builtin_amdgcn_mfma_f32_16x16x32_bf16(pa[kc], bones, sumB, 0, 0, 0);
      __builtin_amdgcn_s_setprio(0);
    }

    // ================= set A (only while ktile < ntA) =================
    if (ktile < ntA){
      f32x4 sacc[4] = {};
      __builtin_amdgcn_s_setprio(1);
      #pragma unroll
      for (int kc = 0; kc < 2; ++kc){
        #pragma unroll
        for (int ct = 0; ct < 4; ++ct){
          int row = ct*16 + lrow;
          int slot = (kc*4 + lk) ^ (row & 7);
          s16x8 bk = *(const s16x8*)&sK[cur][row*64 + slot*8];
          sacc[ct] = __builtin_amdgcn_mfma_f32_16x16x32_bf16(aqA[kc], bk, sacc[ct], 0, 0, 0);
        }
      }
      __builtin_amdgcn_s_setprio(0);

      const bool need_mask = (k0 + 63 > qbaseA);
      #pragma unroll
      for (int ct = 0; ct < 4; ++ct){
        #pragma unroll
        for (int r = 0; r < 4; ++r){
          float v = sacc[ct][r] * 0.125f;
          if (need_mask){
            int qi = qbaseA + lk*4 + r;
            int ki = k0 + ct*16 + lrow;
            if (ki > qi) v = -10000.0f;
          }
          sP[w][lk*4 + r][ct*16 + lrow] = f2bf(__expf(v));
        }
      }

      s16x8 pa[2];
      #pragma unroll
      for (int kc = 0; kc < 2; ++kc)
        pa[kc] = *(const s16x8*)&sP[w][lrow][kc*32 + lk*8];
      __builtin_amdgcn_s_setprio(1);
      #pragma unroll
      for (int dt = 0; dt < 4; ++dt){
        #pragma unroll
        for (int kc = 0; kc < 2; ++kc){
          int row = dt*16 + lrow;
          int slot = (kc*4 + lk) ^ (row & 7);
          s16x8 bv = *(const s16x8*)&sV[cur][row*64 + slot*8];
          oaccA[dt] = __builtin_amdgcn_mfma_f32_16x16x32_bf16(pa[kc], bv, oaccA[dt], 0, 0, 0);
        }
      }
      #pragma unroll
      for (int kc = 0; kc < 2; ++kc)
        sumA = __builtin_amdgcn_mfma_f32_16x16x32_bf16(pa[kc], bones, sumA, 0, 0, 0);
      __builtin_amdgcn_s_setprio(0);
    }

    __syncthreads();                    // release buffer; prefetch drained
    cur ^= 1;
  }

  #pragma unroll
  for (int r = 0; r < 4; ++r){
    float invA = 1.0f / sumA[r];
    float invB = 1.0f / sumB[r];
    int rowA = b*2048 + qbaseA + lk*4 + r;
    int rowB = b*2048 + qbaseB + lk*4 + r;
    #pragma unroll
    for (int dt = 0; dt < 4; ++dt){
      int col = h*64 + dt*16 + lrow;
      ob[(size_t)rowA * 1024 + col] = f2bf(oaccA[dt][r] * invA);
      ob[(size_t)rowB * 1024 + col] = f2bf(oaccB[dt][r] * invB);
    }
  }
}

// -------- LN fused with split-K4 reduce + residual --------------------------
// v = p0+p1+p2+p3 (bf16 partials) + bias + (resid_bf | resid_f); out = LN(v)
__global__ __launch_bounds__(256) void ln_fused(
    const short* __restrict__ p0, const short* __restrict__ p1,
    const short* __restrict__ p2, const short* __restrict__ p3,
    const float* __restrict__ bias,
    const short* __restrict__ resid_bf, const float* __restrict__ resid_f,
    const float* __restrict__ g, const float* __restrict__ b,
    void* __restrict__ out, int bf16_out)
{
  const int row = blockIdx.x;
  const int t = threadIdx.x;
  const size_t base = (size_t)row*1024 + t*4;
  short4 a0 = *(const short4*)(p0 + base);
  short4 a1 = *(const short4*)(p1 + base);
  short4 a2 = *(const short4*)(p2 + base);
  short4 a3 = *(const short4*)(p3 + base);
  float4 bi = *(const float4*)(bias + t*4);
  float r0, r1, r2, r3;
  if (resid_bf){
    short4 rr = *(const short4*)(resid_bf + base);
    r0 = bf2f(rr.x); r1 = bf2f(rr.y); r2 = bf2f(rr.z); r3 = bf2f(rr.w);
  } else {
    float4 rr = *(const float4*)(resid_f + base);
    r0 = rr.x; r1 = rr.y; r2 = rr.z; r3 = rr.w;
  }
  float v0 = bf2f(a0.x) + bf2f(a1.x) + bf2f(a2.x) + bf2f(a3.x) + bi.x + r0;
  float v1 = bf2f(a0.y) + bf2f(a1.y) + bf2f(a2.y) + bf2f(a3.y) + bi.y + r1;
  float v2 = bf2f(a0.z) + bf2f(a1.z) + bf2f(a2.z) + bf2f(a3.z) + bi.z + r2;
  float v3 = bf2f(a0.w) + bf2f(a1.w) + bf2f(a2.w) + bf2f(a3.w) + bi.w + r3;
  float s = v0 + v1 + v2 + v3;
  float q = v0*v0 + v1*v1 + v2*v2 + v3*v3;
  #pragma unroll
  for (int off = 1; off < 64; off <<= 1){
    s += __shfl_xor(s, off, 64);
    q += __shfl_xor(q, off, 64);
  }
  __shared__ float ss[4], sq[4];
  if ((t & 63) == 0){ ss[t >> 6] = s; sq[t >> 6] = q; }
  __syncthreads();
  s = ss[0] + ss[1] + ss[2] + ss[3];
  q = sq[0] + sq[1] + sq[2] + sq[3];
  float mu = s * (1.0f/1024.0f);
  float var = q * (1.0f/1024.0f) - mu*mu;
  float rs = rsqrtf(var + 1e-5f);
  float4 gg = *(const float4*)(g + t*4);
  float4 bb = *(const float4*)(b + t*4);
  float o0 = (v0 - mu)*rs*gg.x + bb.x;
  float o1 = (v1 - mu)*rs*gg.y + bb.y;
  float o2 = (v2 - mu)*rs*gg.z + bb.z;
  float o3 = (v3 - mu)*rs*gg.w + bb.w;
  if (bf16_out){
    short4 o; o.x = f2bf(o0); o.y = f2bf(o1); o.z = f2bf(o2); o.w = f2bf(o3);
    *(short4*)((short*)out + base) = o;
  } else {
    float4 o = {o0, o1, o2, o3};
    *(float4*)((float*)out + base) = o;
  }
}

// ---------------------------------------------------------------------------
extern "C" void kernel_launch(void* const* d_in, const int* in_sizes, int n_in,
                              void* d_out, int out_size, void* d_ws, size_t ws_size,
                              hipStream_t stream) {
  const float* x      = (const float*)d_in[0];
  const float* w_attn = (const float*)d_in[1];
  const float* b_attn = (const float*)d_in[2];
  const float* w_o    = (const float*)d_in[3];
  const float* b_o    = (const float*)d_in[4];
  const float* ln1_g  = (const float*)d_in[5];
  const float* ln1_b  = (const float*)d_in[6];
  const float* w_fc   = (const float*)d_in[7];
  const float* b_fc   = (const float*)d_in[8];
  const float* w_pr   = (const float*)d_in[9];
  const float* b_pr   = (const float*)d_in[10];
  const float* ln2_g  = (const float*)d_in[11];
  const float* ln2_b  = (const float*)d_in[12];

  char* ws = (char*)d_ws;
  const size_t MB = 1048576;
  // lifetimes: high-water 96 MiB
  short* waT  = (short*)(ws + 0);          // 6 MiB  (steps 2-6)
  short* wfT  = (short*)(ws + 6*MB);       // 8 MiB  (steps 2-11)
  short* wpT  = (short*)(ws + 14*MB);      // 8 MiB  (steps 2-12)
  short* woT  = (short*)(ws + 22*MB);      // 2 MiB  (steps 2-9)
  short* xb   = (short*)(ws + 24*MB);      // 8 MiB  (steps 1-6)
  short* vt   = (short*)(ws + 24*MB);      // 8 MiB  (steps 7-8)
  short* pp2  = (short*)(ws + 24*MB);      // 8 MiB  (steps 9-10, 12-13)
  short* qkvb = (short*)(ws + 32*MB);      // 24 MiB (steps 6-8)
  short* fb   = (short*)(ws + 32*MB);      // 32 MiB (steps 11-12)
  short* ob   = (short*)(ws + 56*MB);      // 8 MiB  (steps 8-9)
  short* pp0  = (short*)(ws + 64*MB);      // 8 MiB  (steps 9-10, 12-13)
  short* pp1  = (short*)(ws + 72*MB);      // 8 MiB
  short* nb   = (short*)(ws + 80*MB);      // 8 MiB  (steps 10-13)
  short* pp3  = (short*)(ws + 88*MB);      // 8 MiB  (steps 9-10, 12-13)

  const int M = 4096;

  // 1. x -> bf16
  cvt_f32_bf16<<<dim3(M*1024/1024), dim3(256), 0, stream>>>(x, xb, M*1024);
  // 2-5. weight transposes (f32 [K][N] -> bf16 [N][K])
  wtrans<<<dim3(3072/32, 1024/32), dim3(32,8), 0, stream>>>(w_attn, waT, 1024, 3072);
  wtrans<<<dim3(1024/32, 1024/32), dim3(32,8), 0, stream>>>(w_o,   woT, 1024, 1024);
  wtrans<<<dim3(4096/32, 1024/32), dim3(32,8), 0, stream>>>(w_fc,  wfT, 1024, 4096);
  wtrans<<<dim3(1024/32, 4096/32), dim3(32,8), 0, stream>>>(w_pr,  wpT, 4096, 1024);
  // 6. qkv = x @ w_attn + b_attn  (bf16 out); 24x32 = 768 blocks (3/CU)
  gemm_bf16<<<dim3(3072/GBN, M/GBM), dim3(256), 0, stream>>>(
      xb, waT, b_attn, qkvb, nullptr, nullptr, nullptr, M, 3072, 1024, 0, 1);
  // 7. vt = transpose of V per (b,h)
  vtrans<<<dim3(2048/32, 64/32, 32), dim3(32,8), 0, stream>>>(qkvb, vt);
  // 8. attention -> ob (bf16); merged pairs, 512 blocks
  attn_kernel<<<dim3(512), dim3(256), 0, stream>>>(qkvb, vt, ob);
  // 9. o-proj split-K4: pp0..3 = ob @ w_o partials (bf16); 8x32x4 = 1024 blocks
  gemm_bf16<<<dim3(1024/GBN, M/GBM, 4), dim3(256), 0, stream>>>(
      ob, woT, nullptr, pp0, pp1, pp2, pp3, M, 1024, 1024, 4, 4);
  // 10. n = LN(pp* + b_o + x) -> nb (bf16)
  ln_fused<<<dim3(M), dim3(256), 0, stream>>>(pp0, pp1, pp2, pp3, b_o,
                                              nullptr, x, ln1_g, ln1_b, nb, 1);
  // 11. f = gelu(n @ w_fc + b_fc) -> fb (bf16); 32x32 = 1024 blocks (4/CU)
  gemm_bf16<<<dim3(4096/GBN, M/GBM), dim3(256), 0, stream>>>(
      nb, wfT, b_fc, fb, nullptr, nullptr, nullptr, M, 4096, 1024, 2, 1);
  // 12. r2 split-K4: pp0..3 = fb @ w_pr partials (bf16); 8x32x4 = 1024 blocks
  gemm_bf16<<<dim3(1024/GBN, M/GBM, 4), dim3(256), 0, stream>>>(
      fb, wpT, nullptr, pp0, pp1, pp2, pp3, M, 1024, 4096, 4, 4);
  // 13. h = LN(pp* + b_pr + nb) -> d_out (f32)
  ln_fused<<<dim3(M), dim3(256), 0, stream>>>(pp0, pp1, pp2, pp3, b_pr,
                                              nb, nullptr, ln2_g, ln2_b, d_out, 0);
}